// Round 1
// baseline (922.198 us; speedup 1.0000x reference)
//
#include <hip/hip_runtime.h>

#define N_NODES 100000
#define N_EDGES 3200000
#define FEAT 64
#define NUM_RELS 16

typedef float f32x16 __attribute__((ext_vector_type(16)));

// One wave = one relation. Lane o holds W[rel][:, o] in 64 VGPRs.
// Waves scan the edge list in 64-edge chunks, ballot-filter on rel,
// process matching edges with h[src] in SGPRs (s_load_dwordx16) and
// 64 v_fmac_f32 per edge, then one coalesced global_atomic_add_f32.
__global__ __launch_bounds__(256) void rgcn_edge_kernel(
    const float* __restrict__ h,
    const float* __restrict__ W,
    const float* __restrict__ norm,
    const int* __restrict__ src,
    const int* __restrict__ dst,
    const int* __restrict__ rel,
    float* __restrict__ out)
{
    const int lane        = threadIdx.x & 63;
    const int waveInBlock = threadIdx.x >> 6;
    const int r           = blockIdx.x & 15;          // relation id
    const int inst        = blockIdx.x >> 4;          // instance within relation
    const int wavesPerRel = (gridDim.x >> 4) * 4;
    const int wi          = inst * 4 + waveInBlock;   // wave index within relation

    // Load this relation's weight column: wreg[d] = W[r][d][lane]
    float wreg[64];
    const float* Wr = W + (size_t)r * (FEAT * FEAT) + lane;
    #pragma unroll
    for (int d = 0; d < 64; ++d) wreg[d] = Wr[d * 64];

    const int nChunks = N_EDGES / 64;   // 50000, exact
    for (int c = wi; c < nChunks; c += wavesPerRel) {
        const int base = c * 64;
        const int re = rel[base + lane];
        unsigned long long m = __ballot(re == r);
        while (m) {
            const int idx = __ffsll((unsigned long long)m) - 1;
            m &= (m - 1);
            const int e = base + idx;                  // wave-uniform
            const int se = __builtin_amdgcn_readfirstlane(src[e]);
            const int de = __builtin_amdgcn_readfirstlane(dst[e]);
            const float nv = __uint_as_float(
                __builtin_amdgcn_readfirstlane(__float_as_uint(norm[e])));

            const float* hp = h + ((size_t)se << 6);   // uniform pointer
            f32x16 ha, hb, hc, hd;
            asm volatile(
                "s_load_dwordx16 %0, %4, 0x0\n\t"
                "s_load_dwordx16 %1, %4, 0x40\n\t"
                "s_load_dwordx16 %2, %4, 0x80\n\t"
                "s_load_dwordx16 %3, %4, 0xc0\n\t"
                "s_waitcnt lgkmcnt(0)"
                : "=&s"(ha), "=&s"(hb), "=&s"(hc), "=&s"(hd)
                : "s"(hp));

            float a0 = 0.f, a1 = 0.f, a2 = 0.f, a3 = 0.f;
            #pragma unroll
            for (int j = 0; j < 16; ++j) {
                a0 = fmaf(ha[j], wreg[j],      a0);
                a1 = fmaf(hb[j], wreg[16 + j], a1);
                a2 = fmaf(hc[j], wreg[32 + j], a2);
                a3 = fmaf(hd[j], wreg[48 + j], a3);
            }
            const float v = ((a0 + a1) + (a2 + a3)) * nv;
            unsafeAtomicAdd(&out[(size_t)de * FEAT + lane], v);
        }
    }
}

__global__ __launch_bounds__(256) void relu_kernel(float4* __restrict__ out, int n4)
{
    const int i = blockIdx.x * 256 + threadIdx.x;
    if (i < n4) {
        float4 v = out[i];
        v.x = fmaxf(v.x, 0.f);
        v.y = fmaxf(v.y, 0.f);
        v.z = fmaxf(v.z, 0.f);
        v.w = fmaxf(v.w, 0.f);
        out[i] = v;
    }
}

extern "C" void kernel_launch(void* const* d_in, const int* in_sizes, int n_in,
                              void* d_out, int out_size, void* d_ws, size_t ws_size,
                              hipStream_t stream)
{
    (void)in_sizes; (void)n_in; (void)d_ws; (void)ws_size;

    const float* h    = (const float*)d_in[0];
    const float* W    = (const float*)d_in[1];
    const float* norm = (const float*)d_in[2];
    const int*   src  = (const int*)d_in[3];
    const int*   dst  = (const int*)d_in[4];
    const int*   rel  = (const int*)d_in[5];
    float*       out  = (float*)d_out;

    // Zero the accumulator (we must re-init every call; harness doesn't).
    hipMemsetAsync(d_out, 0, (size_t)out_size * sizeof(float), stream);

    // 16 rels x 128 blocks, 256 threads (4 waves) each.
    dim3 grid(16 * 128), block(256);
    hipLaunchKernelGGL(rgcn_edge_kernel, grid, block, 0, stream,
                       h, W, norm, src, dst, rel, out);

    const int n4 = out_size / 4;
    dim3 rgrid((n4 + 255) / 256), rblock(256);
    hipLaunchKernelGGL(relu_kernel, rgrid, rblock, 0, stream,
                       (float4*)d_out, n4);
}

// Round 2
// 879.869 us; speedup vs baseline: 1.0481x; 1.0481x over previous
//
#include <hip/hip_runtime.h>

#define N_NODES 100000
#define N_EDGES 3200000
#define FEAT 64
#define NUM_RELS 16
#define BLOCKS_PER_REL 256

typedef float f32x4 __attribute__((ext_vector_type(4)));
typedef short s16x8 __attribute__((ext_vector_type(8)));

__device__ __forceinline__ unsigned short f32_to_bf16_rne(float x) {
    unsigned int u = __float_as_uint(x);
    unsigned int r = (u + 0x7fffu + ((u >> 16) & 1u)) >> 16;
    return (unsigned short)r;
}

__global__ __launch_bounds__(256) void cvt_h_kernel(const float4* __restrict__ h4,
                                                    ushort4* __restrict__ hb4, int n4)
{
    int i = blockIdx.x * 256 + threadIdx.x;
    if (i < n4) {
        float4 v = h4[i];
        ushort4 o;
        o.x = f32_to_bf16_rne(v.x); o.y = f32_to_bf16_rne(v.y);
        o.z = f32_to_bf16_rne(v.z); o.w = f32_to_bf16_rne(v.w);
        hb4[i] = o;
    }
}

// Wt[r][o][k] = bf16(W[r][k][o])  (transpose so B-fragments load contiguous K)
__global__ __launch_bounds__(256) void cvt_w_kernel(const float* __restrict__ W,
                                                    unsigned short* __restrict__ Wt)
{
    int t = blockIdx.x * 256 + threadIdx.x;          // exactly 16*64*64 threads
    int r = t >> 12, o = (t >> 6) & 63, k = t & 63;
    Wt[t] = f32_to_bf16_rne(W[(r << 12) + (k << 6) + o]);
}

// One wave = one relation instance. Scan edge list in 64-chunks, ballot-filter,
// queue matches in an LDS ring, fire a 16-edge x 64-out MFMA batch when full.
__global__ __launch_bounds__(256, 4) void rgcn_mfma_kernel(
    const unsigned short* __restrict__ hb,   // h in bf16 [N][64]
    const unsigned short* __restrict__ Wt,   // W^T in bf16 [16][out][in]
    const float* __restrict__ norm,
    const int* __restrict__ src,
    const int* __restrict__ dst,
    const int* __restrict__ rel,
    float* __restrict__ out)
{
    __shared__ int ring[4][128];
    const int lane = threadIdx.x & 63;
    const int w    = threadIdx.x >> 6;
    const int r    = blockIdx.x & 15;
    const int inst = blockIdx.x >> 4;
    const int wavesPerRel = BLOCKS_PER_REL * 4;
    const int wi   = inst * 4 + w;

    // B fragments (held for whole kernel): lane holds col o = t*16+(lane&15),
    // k = kh*32 + (lane>>4)*8 .. +8 (contiguous, matches A's K mapping)
    s16x8 Bf[4][2];
    {
        const unsigned short* wp = Wt + ((size_t)r << 12) + ((size_t)(lane & 15) << 6)
                                      + ((lane >> 4) << 3);
        #pragma unroll
        for (int t = 0; t < 4; ++t)
            #pragma unroll
            for (int kh = 0; kh < 2; ++kh)
                Bf[t][kh] = *reinterpret_cast<const s16x8*>(wp + (t << 10) + (kh << 5));
    }

    auto process16 = [&](int rdp, int nvalid) {
        const int q     = lane & 15;
        const int gbase = (lane >> 4) << 2;
        const int base  = rdp & 127;                 // rdp % 16 == 0, block never wraps
        // A gather: 16 h-rows, lane holds row q, k = (lane>>4)*8 .. +8 (x2 halves)
        int eA = ring[w][base + q];
        int sA = src[eA];
        const unsigned short* hrow = hb + ((size_t)sA << 6) + ((lane >> 4) << 3);
        s16x8 a0 = *reinterpret_cast<const s16x8*>(hrow);
        s16x8 a1 = *reinterpret_cast<const s16x8*>(hrow + 32);
        f32x4 acc[4] = {f32x4{0,0,0,0}, f32x4{0,0,0,0}, f32x4{0,0,0,0}, f32x4{0,0,0,0}};
        #pragma unroll
        for (int t = 0; t < 4; ++t) {
            acc[t] = __builtin_amdgcn_mfma_f32_16x16x32_bf16(a0, Bf[t][0], acc[t], 0, 0, 0);
            acc[t] = __builtin_amdgcn_mfma_f32_16x16x32_bf16(a1, Bf[t][1], acc[t], 0, 0, 0);
        }
        // C rows this lane owns: gbase..gbase+3 ; col = t*16 + q
        int4 ec = *reinterpret_cast<const int4*>(&ring[w][base + gbase]);
        float nv[4]; int dv[4];
        #pragma unroll
        for (int g = 0; g < 4; ++g) {
            int e = (&ec.x)[g];
            nv[g] = ((gbase + g) < nvalid) ? norm[e] : 0.0f;
            dv[g] = dst[e];
        }
        #pragma unroll
        for (int g = 0; g < 4; ++g) {
            float* orow = out + ((size_t)dv[g] << 6) + q;
            #pragma unroll
            for (int t = 0; t < 4; ++t)
                unsafeAtomicAdd(orow + (t << 4), acc[t][g] * nv[g]);
        }
    };

    int wr = 0, rd = 0;
    const int nChunks = N_EDGES / 64;                // 50000 exact
    for (int c = wi; c < nChunks; c += wavesPerRel) {
        int e = (c << 6) + lane;
        bool match = (rel[e] == r);
        unsigned long long m = __ballot(match);
        if (match) {
            int pos = wr + __popcll(m & ((1ull << lane) - 1ull));
            ring[w][pos & 127] = e;
        }
        wr += (int)__popcll(m);
        while (wr - rd >= 16) { process16(rd, 16); rd += 16; }
    }
    if (wr > rd) {                                   // tail: pad ring with a valid id
        int n = wr - rd;
        int efirst = ring[w][rd & 127];
        if (lane < 16 - n) ring[w][(rd & 127) + n + lane] = efirst;
        process16(rd, n);
    }
}

__global__ __launch_bounds__(256) void relu_kernel(float4* __restrict__ out, int n4)
{
    int i = blockIdx.x * 256 + threadIdx.x;
    if (i < n4) {
        float4 v = out[i];
        v.x = fmaxf(v.x, 0.f); v.y = fmaxf(v.y, 0.f);
        v.z = fmaxf(v.z, 0.f); v.w = fmaxf(v.w, 0.f);
        out[i] = v;
    }
}

extern "C" void kernel_launch(void* const* d_in, const int* in_sizes, int n_in,
                              void* d_out, int out_size, void* d_ws, size_t ws_size,
                              hipStream_t stream)
{
    (void)in_sizes; (void)n_in; (void)ws_size;

    const float* h    = (const float*)d_in[0];
    const float* W    = (const float*)d_in[1];
    const float* norm = (const float*)d_in[2];
    const int*   src  = (const int*)d_in[3];
    const int*   dst  = (const int*)d_in[4];
    const int*   rel  = (const int*)d_in[5];
    float*       out  = (float*)d_out;

    unsigned short* hb = (unsigned short*)d_ws;                  // 12.8 MB
    unsigned short* Wt = hb + (size_t)N_NODES * FEAT;            // 128 KB

    // h -> bf16 (vectorized x4)
    const int n4h = N_NODES * FEAT / 4;                          // 1,600,000
    hipLaunchKernelGGL(cvt_h_kernel, dim3((n4h + 255) / 256), dim3(256), 0, stream,
                       (const float4*)h, (ushort4*)hb, n4h);
    // W -> bf16 transposed
    hipLaunchKernelGGL(cvt_w_kernel, dim3(NUM_RELS * FEAT * FEAT / 256), dim3(256), 0, stream,
                       W, Wt);
    // zero accumulator
    hipMemsetAsync(d_out, 0, (size_t)out_size * sizeof(float), stream);

    hipLaunchKernelGGL(rgcn_mfma_kernel, dim3(NUM_RELS * BLOCKS_PER_REL), dim3(256), 0, stream,
                       hb, Wt, norm, src, dst, rel, out);

    const int n4 = out_size / 4;
    hipLaunchKernelGGL(relu_kernel, dim3((n4 + 255) / 256), dim3(256), 0, stream,
                       (float4*)d_out, n4);
}

// Round 3
// 614.311 us; speedup vs baseline: 1.5012x; 1.4323x over previous
//
#include <hip/hip_runtime.h>

#define N_NODES 100000
#define N_EDGES 3200000
#define FEAT 64
#define NUM_RELS 16

typedef float f32x4 __attribute__((ext_vector_type(4)));
typedef float f32x16 __attribute__((ext_vector_type(16)));
typedef short s16x8 __attribute__((ext_vector_type(8)));

__device__ __forceinline__ unsigned short f32_to_bf16_rne(float x) {
    unsigned int u = __float_as_uint(x);
    unsigned int r = (u + 0x7fffu + ((u >> 16) & 1u)) >> 16;
    return (unsigned short)r;
}
__device__ __forceinline__ float bf16_to_f32(unsigned short s) {
    return __uint_as_float(((unsigned int)s) << 16);
}

// ---------------- conversion kernels ----------------
__global__ __launch_bounds__(256) void cvt_h_kernel(const float4* __restrict__ h4,
                                                    ushort4* __restrict__ hb4, int n4)
{
    int i = blockIdx.x * 256 + threadIdx.x;
    if (i < n4) {
        float4 v = h4[i];
        ushort4 o;
        o.x = f32_to_bf16_rne(v.x); o.y = f32_to_bf16_rne(v.y);
        o.z = f32_to_bf16_rne(v.z); o.w = f32_to_bf16_rne(v.w);
        hb4[i] = o;
    }
}

// Wt[r][o][k] = bf16(W[r][k][o])
__global__ __launch_bounds__(256) void cvt_w_kernel(const float* __restrict__ W,
                                                    unsigned short* __restrict__ Wt)
{
    int t = blockIdx.x * 256 + threadIdx.x;          // 16*64*64 threads
    int r = t >> 12, o = (t >> 6) & 63, k = t & 63;
    Wt[t] = f32_to_bf16_rne(W[(r << 12) + (k << 6) + o]);
}

// ---------------- phase 1: dense transform T[n][r][o] = (h[n] @ W[r])  (bf16) ----
__global__ __launch_bounds__(256) void gemm_T_kernel(
    const unsigned short* __restrict__ hb,   // [N][64] bf16
    const unsigned short* __restrict__ Wt,   // [16][o][k] bf16
    unsigned short* __restrict__ T)          // [N][16][64] bf16
{
    const int lane  = threadIdx.x & 63;
    const int w     = threadIdx.x >> 6;
    const int row0  = blockIdx.x * 64 + w * 16;      // this wave's 16 rows
    const int q     = lane & 15;
    const int g4    = lane >> 4;
    const int gbase = g4 << 2;

    // A fragments: lane holds row row0+q, k = g4*8..+8 (a0: k<32, a1: k>=32)
    const int rowA = min(row0 + q, N_NODES - 1);
    const unsigned short* ap = hb + ((size_t)rowA << 6) + (g4 << 3);
    const s16x8 a0 = *reinterpret_cast<const s16x8*>(ap);
    const s16x8 a1 = *reinterpret_cast<const s16x8*>(ap + 32);

    const unsigned short* wbase = Wt + ((size_t)q << 6) + (g4 << 3);

    auto loadB = [&](s16x8* Bf, int r) {
        const unsigned short* wp = wbase + ((size_t)r << 12);
        #pragma unroll
        for (int t = 0; t < 4; ++t)
            #pragma unroll
            for (int kh = 0; kh < 2; ++kh)
                Bf[t * 2 + kh] = *reinterpret_cast<const s16x8*>(wp + (t << 10) + (kh << 5));
    };
    auto compStore = [&](const s16x8* Bf, int r) {
        f32x4 acc[4] = {f32x4{0,0,0,0}, f32x4{0,0,0,0}, f32x4{0,0,0,0}, f32x4{0,0,0,0}};
        #pragma unroll
        for (int t = 0; t < 4; ++t) {
            acc[t] = __builtin_amdgcn_mfma_f32_16x16x32_bf16(a0, Bf[t*2+0], acc[t], 0, 0, 0);
            acc[t] = __builtin_amdgcn_mfma_f32_16x16x32_bf16(a1, Bf[t*2+1], acc[t], 0, 0, 0);
        }
        #pragma unroll
        for (int g = 0; g < 4; ++g) {
            const int rowc = row0 + gbase + g;
            if (rowc < N_NODES) {
                #pragma unroll
                for (int t = 0; t < 4; ++t)
                    T[((size_t)rowc << 10) + (r << 6) + (t << 4) + q] =
                        f32_to_bf16_rne(acc[t][g]);
            }
        }
    };

    s16x8 B0[8], B1[8];
    loadB(B0, 0);
    #pragma unroll
    for (int rp = 0; rp < 16; rp += 2) {
        loadB(B1, rp + 1);
        compStore(B0, rp);
        if (rp + 2 < 16) loadB(B0, rp + 2);
        compStore(B1, rp + 1);
    }
}

// ---------------- phase 2: CSR by dst ----------------
__global__ __launch_bounds__(256) void hist_kernel(const int* __restrict__ dst,
                                                   int* __restrict__ cnt)
{
    int e = blockIdx.x * 256 + threadIdx.x;
    if (e < N_EDGES) atomicAdd(&cnt[dst[e]], 1);
}

__global__ __launch_bounds__(1024) void scan1_kernel(const int* __restrict__ cnt,
                                                     int* __restrict__ ofs,
                                                     int* __restrict__ btot, int n)
{
    __shared__ int tmp[1024];
    const int tid = threadIdx.x;
    const int i = blockIdx.x * 1024 + tid;
    int v = (i < n) ? cnt[i] : 0;
    tmp[tid] = v; __syncthreads();
    #pragma unroll
    for (int off = 1; off < 1024; off <<= 1) {
        int t = (tid >= off) ? tmp[tid - off] : 0;
        __syncthreads();
        tmp[tid] += t;
        __syncthreads();
    }
    if (i < n) ofs[i] = tmp[tid] - v;          // exclusive within block
    if (tid == 1023) btot[blockIdx.x] = tmp[tid];
}

__global__ __launch_bounds__(128) void scan2_kernel(int* __restrict__ btot,
                                                    int* __restrict__ bbase, int nb)
{
    __shared__ int tmp[128];
    const int tid = threadIdx.x;
    int v = (tid < nb) ? btot[tid] : 0;
    tmp[tid] = v; __syncthreads();
    #pragma unroll
    for (int off = 1; off < 128; off <<= 1) {
        int t = (tid >= off) ? tmp[tid - off] : 0;
        __syncthreads();
        tmp[tid] += t;
        __syncthreads();
    }
    if (tid < nb) bbase[tid] = tmp[tid] - v;   // exclusive
}

__global__ __launch_bounds__(1024) void scan3_kernel(int* __restrict__ ofs,
                                                     int* __restrict__ cur,
                                                     const int* __restrict__ bbase, int n)
{
    const int i = blockIdx.x * 1024 + threadIdx.x;
    if (i < n) {
        int o = ofs[i] + bbase[blockIdx.x];
        ofs[i] = o;
        cur[i] = o;
    }
    if (i == 0) ofs[n] = N_EDGES;
}

__global__ __launch_bounds__(256) void fill_kernel(const int* __restrict__ src,
                                                   const int* __restrict__ dst,
                                                   const int* __restrict__ rel,
                                                   const float* __restrict__ norm,
                                                   int* __restrict__ cur,
                                                   int2* __restrict__ pay)
{
    int e = blockIdx.x * 256 + threadIdx.x;
    if (e < N_EDGES) {
        int d = dst[e];
        int pos = atomicAdd(&cur[d], 1);
        pay[pos] = make_int2((src[e] << 4) | rel[e], __float_as_int(norm[e]));
    }
}

// ---------------- phase 3: per-dst gather/sum + relu (one wave per node) --------
__global__ __launch_bounds__(256) void aggregate_kernel(
    const unsigned short* __restrict__ T,    // [N][16][64] bf16
    const int2* __restrict__ pay,            // [E] {src*16+rel, norm}
    const int* __restrict__ ofs,             // [N+1]
    float* __restrict__ out)                 // [N][64]
{
    const int lane = threadIdx.x & 63;
    const int d    = blockIdx.x * 4 + (threadIdx.x >> 6);   // grid covers N exactly

    const int beg = __builtin_amdgcn_readfirstlane(ofs[d]);
    const int end = __builtin_amdgcn_readfirstlane(ofs[d + 1]);

    float acc = 0.f;
    int i = beg;
    for (; i + 4 <= end; i += 4) {
        int2 p0 = pay[i], p1 = pay[i + 1], p2 = pay[i + 2], p3 = pay[i + 3];
        const unsigned short t0 = T[((size_t)(p0.x >> 4) << 10) + ((p0.x & 15) << 6) + lane];
        const unsigned short t1 = T[((size_t)(p1.x >> 4) << 10) + ((p1.x & 15) << 6) + lane];
        const unsigned short t2 = T[((size_t)(p2.x >> 4) << 10) + ((p2.x & 15) << 6) + lane];
        const unsigned short t3 = T[((size_t)(p3.x >> 4) << 10) + ((p3.x & 15) << 6) + lane];
        acc = fmaf(__int_as_float(p0.y), bf16_to_f32(t0), acc);
        acc = fmaf(__int_as_float(p1.y), bf16_to_f32(t1), acc);
        acc = fmaf(__int_as_float(p2.y), bf16_to_f32(t2), acc);
        acc = fmaf(__int_as_float(p3.y), bf16_to_f32(t3), acc);
    }
    for (; i < end; ++i) {
        int2 p = pay[i];
        const unsigned short t = T[((size_t)(p.x >> 4) << 10) + ((p.x & 15) << 6) + lane];
        acc = fmaf(__int_as_float(p.y), bf16_to_f32(t), acc);
    }
    out[((size_t)d << 6) + lane] = fmaxf(acc, 0.f);
}

// ---------------- fallback (round-1 path, no workspace needed) ----------------
__global__ __launch_bounds__(256) void rgcn_edge_kernel(
    const float* __restrict__ h, const float* __restrict__ W,
    const float* __restrict__ norm, const int* __restrict__ src,
    const int* __restrict__ dst, const int* __restrict__ rel,
    float* __restrict__ out)
{
    const int lane = threadIdx.x & 63;
    const int w    = threadIdx.x >> 6;
    const int r    = blockIdx.x & 15;
    const int inst = blockIdx.x >> 4;
    const int wavesPerRel = (gridDim.x >> 4) * 4;
    const int wi   = inst * 4 + w;

    float wreg[64];
    const float* Wr = W + (size_t)r * (FEAT * FEAT) + lane;
    #pragma unroll
    for (int d = 0; d < 64; ++d) wreg[d] = Wr[d * 64];

    const int nChunks = N_EDGES / 64;
    for (int c = wi; c < nChunks; c += wavesPerRel) {
        const int base = c * 64;
        unsigned long long m = __ballot(rel[base + lane] == r);
        while (m) {
            const int idx = __ffsll(m) - 1;
            m &= (m - 1);
            const int e = base + idx;
            const int se = __builtin_amdgcn_readfirstlane(src[e]);
            const int de = __builtin_amdgcn_readfirstlane(dst[e]);
            const float nv = __uint_as_float(
                __builtin_amdgcn_readfirstlane(__float_as_uint(norm[e])));
            const float* hp = h + ((size_t)se << 6);
            f32x16 ha, hb2, hc, hd;
            asm volatile(
                "s_load_dwordx16 %0, %4, 0x0\n\ts_load_dwordx16 %1, %4, 0x40\n\t"
                "s_load_dwordx16 %2, %4, 0x80\n\ts_load_dwordx16 %3, %4, 0xc0\n\t"
                "s_waitcnt lgkmcnt(0)"
                : "=&s"(ha), "=&s"(hb2), "=&s"(hc), "=&s"(hd) : "s"(hp));
            float a0 = 0.f, a1 = 0.f, a2 = 0.f, a3 = 0.f;
            #pragma unroll
            for (int j = 0; j < 16; ++j) {
                a0 = fmaf(ha[j], wreg[j], a0);       a1 = fmaf(hb2[j], wreg[16 + j], a1);
                a2 = fmaf(hc[j], wreg[32 + j], a2);  a3 = fmaf(hd[j], wreg[48 + j], a3);
            }
            unsafeAtomicAdd(&out[(size_t)de * FEAT + lane], ((a0 + a1) + (a2 + a3)) * nv);
        }
    }
}

__global__ __launch_bounds__(256) void relu_kernel(float4* __restrict__ out, int n4)
{
    int i = blockIdx.x * 256 + threadIdx.x;
    if (i < n4) {
        float4 v = out[i];
        v.x = fmaxf(v.x, 0.f); v.y = fmaxf(v.y, 0.f);
        v.z = fmaxf(v.z, 0.f); v.w = fmaxf(v.w, 0.f);
        out[i] = v;
    }
}

// ---------------- host ----------------
static inline size_t align256(size_t x) { return (x + 255) & ~(size_t)255; }

extern "C" void kernel_launch(void* const* d_in, const int* in_sizes, int n_in,
                              void* d_out, int out_size, void* d_ws, size_t ws_size,
                              hipStream_t stream)
{
    (void)in_sizes; (void)n_in;

    const float* h    = (const float*)d_in[0];
    const float* W    = (const float*)d_in[1];
    const float* norm = (const float*)d_in[2];
    const int*   src  = (const int*)d_in[3];
    const int*   dst  = (const int*)d_in[4];
    const int*   rel  = (const int*)d_in[5];
    float*       out  = (float*)d_out;

    // workspace layout
    size_t off = 0;
    const size_t szT    = (size_t)N_NODES * NUM_RELS * FEAT * 2;   // 204.8 MB
    const size_t szHb   = (size_t)N_NODES * FEAT * 2;              // 12.8 MB
    const size_t szWt   = (size_t)NUM_RELS * FEAT * FEAT * 2;      // 128 KB
    const size_t szPay  = (size_t)N_EDGES * 8;                     // 25.6 MB
    const size_t szCnt  = (size_t)N_NODES * 4;
    const size_t szOfs  = (size_t)(N_NODES + 1) * 4;
    const size_t need = align256(szT) + align256(szHb) + align256(szWt) + align256(szPay)
                      + 3 * align256(szCnt) + align256(szOfs) + 2 * align256(1024);

    if (ws_size < need) {
        // fallback: round-1 atomic path (no workspace)
        hipMemsetAsync(d_out, 0, (size_t)out_size * sizeof(float), stream);
        hipLaunchKernelGGL(rgcn_edge_kernel, dim3(16 * 128), dim3(256), 0, stream,
                           h, W, norm, src, dst, rel, out);
        const int n4 = out_size / 4;
        hipLaunchKernelGGL(relu_kernel, dim3((n4 + 255) / 256), dim3(256), 0, stream,
                           (float4*)d_out, n4);
        return;
    }

    char* ws = (char*)d_ws;
    unsigned short* T   = (unsigned short*)(ws + off); off += align256(szT);
    unsigned short* hb  = (unsigned short*)(ws + off); off += align256(szHb);
    unsigned short* Wt  = (unsigned short*)(ws + off); off += align256(szWt);
    int2*           pay = (int2*)          (ws + off); off += align256(szPay);
    int*            cnt = (int*)           (ws + off); off += align256(szCnt);
    int*            ofs = (int*)           (ws + off); off += align256(szOfs);
    int*            cur = (int*)           (ws + off); off += align256(szCnt);
    int*            btot= (int*)           (ws + off); off += align256(1024);
    int*            bbas= (int*)           (ws + off); off += align256(1024);

    // conversions
    const int n4h = N_NODES * FEAT / 4;
    hipLaunchKernelGGL(cvt_h_kernel, dim3((n4h + 255) / 256), dim3(256), 0, stream,
                       (const float4*)h, (ushort4*)hb, n4h);
    hipLaunchKernelGGL(cvt_w_kernel, dim3(NUM_RELS * FEAT * FEAT / 256), dim3(256), 0, stream,
                       W, Wt);
    hipMemsetAsync(cnt, 0, szCnt, stream);

    // phase 1: dense transform
    hipLaunchKernelGGL(gemm_T_kernel, dim3((N_NODES + 63) / 64), dim3(256), 0, stream,
                       hb, Wt, T);

    // phase 2: CSR by dst
    hipLaunchKernelGGL(hist_kernel, dim3((N_EDGES + 255) / 256), dim3(256), 0, stream,
                       dst, cnt);
    const int nBlocksScan = (N_NODES + 1023) / 1024;     // 98
    hipLaunchKernelGGL(scan1_kernel, dim3(nBlocksScan), dim3(1024), 0, stream,
                       cnt, ofs, btot, N_NODES);
    hipLaunchKernelGGL(scan2_kernel, dim3(1), dim3(128), 0, stream,
                       btot, bbas, nBlocksScan);
    hipLaunchKernelGGL(scan3_kernel, dim3(nBlocksScan), dim3(1024), 0, stream,
                       ofs, cur, bbas, N_NODES);
    hipLaunchKernelGGL(fill_kernel, dim3((N_EDGES + 255) / 256), dim3(256), 0, stream,
                       src, dst, rel, norm, cur, pay);

    // phase 3: aggregate + relu (each output written exactly once)
    hipLaunchKernelGGL(aggregate_kernel, dim3(N_NODES / 4), dim3(256), 0, stream,
                       T, pay, ofs, out);
}

// Round 5
// 596.362 us; speedup vs baseline: 1.5464x; 1.0301x over previous
//
#include <hip/hip_runtime.h>

#define N_NODES 100000
#define N_EDGES 3200000
#define FEAT 64
#define NUM_RELS 16
#define N_RANGES 8

typedef float f32x4 __attribute__((ext_vector_type(4)));
typedef float f32x16 __attribute__((ext_vector_type(16)));
typedef short s16x8 __attribute__((ext_vector_type(8)));
typedef int   i32x2 __attribute__((ext_vector_type(2)));

__device__ __forceinline__ unsigned short f32_to_bf16_rne(float x) {
    unsigned int u = __float_as_uint(x);
    unsigned int r = (u + 0x7fffu + ((u >> 16) & 1u)) >> 16;
    return (unsigned short)r;
}
__device__ __forceinline__ float bf16_to_f32(unsigned short s) {
    return __uint_as_float(((unsigned int)s) << 16);
}

// ---------------- conversion kernels ----------------
__global__ __launch_bounds__(256) void cvt_h_kernel(const float4* __restrict__ h4,
                                                    ushort4* __restrict__ hb4, int n4)
{
    int i = blockIdx.x * 256 + threadIdx.x;
    if (i < n4) {
        float4 v = h4[i];
        ushort4 o;
        o.x = f32_to_bf16_rne(v.x); o.y = f32_to_bf16_rne(v.y);
        o.z = f32_to_bf16_rne(v.z); o.w = f32_to_bf16_rne(v.w);
        hb4[i] = o;
    }
}

// Wt[r][o][k] = bf16(W[r][k][o])
__global__ __launch_bounds__(256) void cvt_w_kernel(const float* __restrict__ W,
                                                    unsigned short* __restrict__ Wt)
{
    int t = blockIdx.x * 256 + threadIdx.x;          // 16*64*64 threads
    int r = t >> 12, o = (t >> 6) & 63, k = t & 63;
    Wt[t] = f32_to_bf16_rne(W[(r << 12) + (k << 6) + o]);
}

// ---------------- phase 1: dense transform T[n][r][o] = (h[n] @ W[r])  (bf16) ----
__global__ __launch_bounds__(256) void gemm_T_kernel(
    const unsigned short* __restrict__ hb,   // [N][64] bf16
    const unsigned short* __restrict__ Wt,   // [16][o][k] bf16
    unsigned short* __restrict__ T)          // [N][16][64] bf16
{
    const int lane  = threadIdx.x & 63;
    const int w     = threadIdx.x >> 6;
    const int row0  = blockIdx.x * 64 + w * 16;      // this wave's 16 rows
    const int q     = lane & 15;
    const int g4    = lane >> 4;
    const int gbase = g4 << 2;

    const int rowA = min(row0 + q, N_NODES - 1);
    const unsigned short* ap = hb + ((size_t)rowA << 6) + (g4 << 3);
    const s16x8 a0 = *reinterpret_cast<const s16x8*>(ap);
    const s16x8 a1 = *reinterpret_cast<const s16x8*>(ap + 32);

    const unsigned short* wbase = Wt + ((size_t)q << 6) + (g4 << 3);

    auto loadB = [&](s16x8* Bf, int r) {
        const unsigned short* wp = wbase + ((size_t)r << 12);
        #pragma unroll
        for (int t = 0; t < 4; ++t)
            #pragma unroll
            for (int kh = 0; kh < 2; ++kh)
                Bf[t * 2 + kh] = *reinterpret_cast<const s16x8*>(wp + (t << 10) + (kh << 5));
    };
    auto compStore = [&](const s16x8* Bf, int r) {
        f32x4 acc[4] = {f32x4{0,0,0,0}, f32x4{0,0,0,0}, f32x4{0,0,0,0}, f32x4{0,0,0,0}};
        #pragma unroll
        for (int t = 0; t < 4; ++t) {
            acc[t] = __builtin_amdgcn_mfma_f32_16x16x32_bf16(a0, Bf[t*2+0], acc[t], 0, 0, 0);
            acc[t] = __builtin_amdgcn_mfma_f32_16x16x32_bf16(a1, Bf[t*2+1], acc[t], 0, 0, 0);
        }
        #pragma unroll
        for (int g = 0; g < 4; ++g) {
            const int rowc = row0 + gbase + g;
            if (rowc < N_NODES) {
                #pragma unroll
                for (int t = 0; t < 4; ++t)
                    __builtin_nontemporal_store(f32_to_bf16_rne(acc[t][g]),
                        &T[((size_t)rowc << 10) + (r << 6) + (t << 4) + q]);
            }
        }
    };

    s16x8 B0[8], B1[8];
    loadB(B0, 0);
    #pragma unroll
    for (int rp = 0; rp < 16; rp += 2) {
        loadB(B1, rp + 1);
        compStore(B0, rp);
        if (rp + 2 < 16) loadB(B0, rp + 2);
        compStore(B1, rp + 1);
    }
}

// ---------------- phase 2: CSR by dst ----------------
__global__ __launch_bounds__(256) void hist_kernel(const int* __restrict__ dst,
                                                   int* __restrict__ cnt)
{
    int e = blockIdx.x * 256 + threadIdx.x;
    if (e < N_EDGES) atomicAdd(&cnt[__builtin_nontemporal_load(&dst[e])], 1);
}

__global__ __launch_bounds__(1024) void scan1_kernel(const int* __restrict__ cnt,
                                                     int* __restrict__ ofs,
                                                     int* __restrict__ btot, int n)
{
    __shared__ int tmp[1024];
    const int tid = threadIdx.x;
    const int i = blockIdx.x * 1024 + tid;
    int v = (i < n) ? cnt[i] : 0;
    tmp[tid] = v; __syncthreads();
    #pragma unroll
    for (int off = 1; off < 1024; off <<= 1) {
        int t = (tid >= off) ? tmp[tid - off] : 0;
        __syncthreads();
        tmp[tid] += t;
        __syncthreads();
    }
    if (i < n) ofs[i] = tmp[tid] - v;          // exclusive within block
    if (tid == 1023) btot[blockIdx.x] = tmp[tid];
}

__global__ __launch_bounds__(128) void scan2_kernel(int* __restrict__ btot,
                                                    int* __restrict__ bbase, int nb)
{
    __shared__ int tmp[128];
    const int tid = threadIdx.x;
    int v = (tid < nb) ? btot[tid] : 0;
    tmp[tid] = v; __syncthreads();
    #pragma unroll
    for (int off = 1; off < 128; off <<= 1) {
        int t = (tid >= off) ? tmp[tid - off] : 0;
        __syncthreads();
        tmp[tid] += t;
        __syncthreads();
    }
    if (tid < nb) bbase[tid] = tmp[tid] - v;   // exclusive
}

__global__ __launch_bounds__(1024) void scan3_kernel(int* __restrict__ ofs,
                                                     int* __restrict__ cur,
                                                     const int* __restrict__ bbase, int n)
{
    const int i = blockIdx.x * 1024 + threadIdx.x;
    if (i < n) {
        int o = ofs[i] + bbase[blockIdx.x];
        ofs[i] = o;
        cur[i] = o;
    }
    if (i == 0) ofs[n] = N_EDGES;
}

// Range-split payload scatter: only edges with dst in [lo,hi) are placed.
// Keeps the live pay window small (~3.2 MB) so L2 lines accumulate all their
// entries before writeback; nt loads keep the streams from evicting pay lines.
__global__ __launch_bounds__(256) void fill_kernel(const int* __restrict__ src,
                                                   const int* __restrict__ dst,
                                                   const int* __restrict__ rel,
                                                   const float* __restrict__ norm,
                                                   int* __restrict__ cur,
                                                   i32x2* __restrict__ pay,
                                                   int lo, int hi)
{
    int e = blockIdx.x * 256 + threadIdx.x;
    if (e < N_EDGES) {
        int d = __builtin_nontemporal_load(&dst[e]);
        if (d >= lo && d < hi) {
            int s  = __builtin_nontemporal_load(&src[e]);
            int rl = __builtin_nontemporal_load(&rel[e]);
            float nv = __builtin_nontemporal_load(&norm[e]);
            int pos = atomicAdd(&cur[d], 1);
            i32x2 p; p.x = (s << 4) | rl; p.y = __float_as_int(nv);
            pay[pos] = p;
        }
    }
}

// ---------------- phase 3: per-dst gather/sum + relu (one wave per node) --------
__global__ __launch_bounds__(256) void aggregate_kernel(
    const unsigned short* __restrict__ T,    // [N][16][64] bf16
    const i32x2* __restrict__ pay,           // [E] {src*16+rel, norm}
    const int* __restrict__ ofs,             // [N+1]
    float* __restrict__ out)                 // [N][64]
{
    const int lane = threadIdx.x & 63;
    const int d    = blockIdx.x * 4 + (threadIdx.x >> 6);   // grid covers N exactly

    const int beg = __builtin_amdgcn_readfirstlane(ofs[d]);
    const int end = __builtin_amdgcn_readfirstlane(ofs[d + 1]);

    float acc = 0.f;
    int i = beg;
    for (; i + 4 <= end; i += 4) {
        i32x2 p0 = __builtin_nontemporal_load(&pay[i]);
        i32x2 p1 = __builtin_nontemporal_load(&pay[i + 1]);
        i32x2 p2 = __builtin_nontemporal_load(&pay[i + 2]);
        i32x2 p3 = __builtin_nontemporal_load(&pay[i + 3]);
        const unsigned short t0 = T[((size_t)(p0.x >> 4) << 10) + ((p0.x & 15) << 6) + lane];
        const unsigned short t1 = T[((size_t)(p1.x >> 4) << 10) + ((p1.x & 15) << 6) + lane];
        const unsigned short t2 = T[((size_t)(p2.x >> 4) << 10) + ((p2.x & 15) << 6) + lane];
        const unsigned short t3 = T[((size_t)(p3.x >> 4) << 10) + ((p3.x & 15) << 6) + lane];
        acc = fmaf(__int_as_float(p0.y), bf16_to_f32(t0), acc);
        acc = fmaf(__int_as_float(p1.y), bf16_to_f32(t1), acc);
        acc = fmaf(__int_as_float(p2.y), bf16_to_f32(t2), acc);
        acc = fmaf(__int_as_float(p3.y), bf16_to_f32(t3), acc);
    }
    for (; i < end; ++i) {
        i32x2 p = __builtin_nontemporal_load(&pay[i]);
        const unsigned short t = T[((size_t)(p.x >> 4) << 10) + ((p.x & 15) << 6) + lane];
        acc = fmaf(__int_as_float(p.y), bf16_to_f32(t), acc);
    }
    out[((size_t)d << 6) + lane] = fmaxf(acc, 0.f);
}

// ---------------- fallback (round-1 path, no workspace needed) ----------------
__global__ __launch_bounds__(256) void rgcn_edge_kernel(
    const float* __restrict__ h, const float* __restrict__ W,
    const float* __restrict__ norm, const int* __restrict__ src,
    const int* __restrict__ dst, const int* __restrict__ rel,
    float* __restrict__ out)
{
    const int lane = threadIdx.x & 63;
    const int w    = threadIdx.x >> 6;
    const int r    = blockIdx.x & 15;
    const int inst = blockIdx.x >> 4;
    const int wavesPerRel = (gridDim.x >> 4) * 4;
    const int wi   = inst * 4 + w;

    float wreg[64];
    const float* Wr = W + (size_t)r * (FEAT * FEAT) + lane;
    #pragma unroll
    for (int d = 0; d < 64; ++d) wreg[d] = Wr[d * 64];

    const int nChunks = N_EDGES / 64;
    for (int c = wi; c < nChunks; c += wavesPerRel) {
        const int base = c * 64;
        unsigned long long m = __ballot(rel[base + lane] == r);
        while (m) {
            const int idx = __ffsll(m) - 1;
            m &= (m - 1);
            const int e = base + idx;
            const int se = __builtin_amdgcn_readfirstlane(src[e]);
            const int de = __builtin_amdgcn_readfirstlane(dst[e]);
            const float nv = __uint_as_float(
                __builtin_amdgcn_readfirstlane(__float_as_uint(norm[e])));
            const float* hp = h + ((size_t)se << 6);
            f32x16 ha, hb2, hc, hd;
            asm volatile(
                "s_load_dwordx16 %0, %4, 0x0\n\ts_load_dwordx16 %1, %4, 0x40\n\t"
                "s_load_dwordx16 %2, %4, 0x80\n\ts_load_dwordx16 %3, %4, 0xc0\n\t"
                "s_waitcnt lgkmcnt(0)"
                : "=&s"(ha), "=&s"(hb2), "=&s"(hc), "=&s"(hd) : "s"(hp));
            float a0 = 0.f, a1 = 0.f, a2 = 0.f, a3 = 0.f;
            #pragma unroll
            for (int j = 0; j < 16; ++j) {
                a0 = fmaf(ha[j], wreg[j], a0);       a1 = fmaf(hb2[j], wreg[16 + j], a1);
                a2 = fmaf(hc[j], wreg[32 + j], a2);  a3 = fmaf(hd[j], wreg[48 + j], a3);
            }
            unsafeAtomicAdd(&out[(size_t)de * FEAT + lane], ((a0 + a1) + (a2 + a3)) * nv);
        }
    }
}

__global__ __launch_bounds__(256) void relu_kernel(float4* __restrict__ out, int n4)
{
    int i = blockIdx.x * 256 + threadIdx.x;
    if (i < n4) {
        float4 v = out[i];
        v.x = fmaxf(v.x, 0.f); v.y = fmaxf(v.y, 0.f);
        v.z = fmaxf(v.z, 0.f); v.w = fmaxf(v.w, 0.f);
        out[i] = v;
    }
}

// ---------------- host ----------------
static inline size_t align256(size_t x) { return (x + 255) & ~(size_t)255; }

extern "C" void kernel_launch(void* const* d_in, const int* in_sizes, int n_in,
                              void* d_out, int out_size, void* d_ws, size_t ws_size,
                              hipStream_t stream)
{
    (void)in_sizes; (void)n_in;

    const float* h    = (const float*)d_in[0];
    const float* W    = (const float*)d_in[1];
    const float* norm = (const float*)d_in[2];
    const int*   src  = (const int*)d_in[3];
    const int*   dst  = (const int*)d_in[4];
    const int*   rel  = (const int*)d_in[5];
    float*       out  = (float*)d_out;

    // workspace layout
    size_t off = 0;
    const size_t szT    = (size_t)N_NODES * NUM_RELS * FEAT * 2;   // 204.8 MB
    const size_t szHb   = (size_t)N_NODES * FEAT * 2;              // 12.8 MB
    const size_t szWt   = (size_t)NUM_RELS * FEAT * FEAT * 2;      // 128 KB
    const size_t szPay  = (size_t)N_EDGES * 8;                     // 25.6 MB
    const size_t szCnt  = (size_t)N_NODES * 4;
    const size_t szOfs  = (size_t)(N_NODES + 1) * 4;
    const size_t need = align256(szT) + align256(szHb) + align256(szWt) + align256(szPay)
                      + 3 * align256(szCnt) + align256(szOfs) + 2 * align256(1024);

    if (ws_size < need) {
        hipMemsetAsync(d_out, 0, (size_t)out_size * sizeof(float), stream);
        hipLaunchKernelGGL(rgcn_edge_kernel, dim3(16 * 128), dim3(256), 0, stream,
                           h, W, norm, src, dst, rel, out);
        const int n4 = out_size / 4;
        hipLaunchKernelGGL(relu_kernel, dim3((n4 + 255) / 256), dim3(256), 0, stream,
                           (float4*)d_out, n4);
        return;
    }

    char* ws = (char*)d_ws;
    unsigned short* T   = (unsigned short*)(ws + off); off += align256(szT);
    unsigned short* hb  = (unsigned short*)(ws + off); off += align256(szHb);
    unsigned short* Wt  = (unsigned short*)(ws + off); off += align256(szWt);
    i32x2*          pay = (i32x2*)         (ws + off); off += align256(szPay);
    int*            cnt = (int*)           (ws + off); off += align256(szCnt);
    int*            ofs = (int*)           (ws + off); off += align256(szOfs);
    int*            cur = (int*)           (ws + off); off += align256(szCnt);
    int*            btot= (int*)           (ws + off); off += align256(1024);
    int*            bbas= (int*)           (ws + off); off += align256(1024);

    // conversions
    const int n4h = N_NODES * FEAT / 4;
    hipLaunchKernelGGL(cvt_h_kernel, dim3((n4h + 255) / 256), dim3(256), 0, stream,
                       (const float4*)h, (ushort4*)hb, n4h);
    hipLaunchKernelGGL(cvt_w_kernel, dim3(NUM_RELS * FEAT * FEAT / 256), dim3(256), 0, stream,
                       W, Wt);
    hipMemsetAsync(cnt, 0, szCnt, stream);

    // phase 1: dense transform
    hipLaunchKernelGGL(gemm_T_kernel, dim3((N_NODES + 63) / 64), dim3(256), 0, stream,
                       hb, Wt, T);

    // phase 2: CSR by dst
    hipLaunchKernelGGL(hist_kernel, dim3((N_EDGES + 255) / 256), dim3(256), 0, stream,
                       dst, cnt);
    const int nBlocksScan = (N_NODES + 1023) / 1024;     // 98
    hipLaunchKernelGGL(scan1_kernel, dim3(nBlocksScan), dim3(1024), 0, stream,
                       cnt, ofs, btot, N_NODES);
    hipLaunchKernelGGL(scan2_kernel, dim3(1), dim3(128), 0, stream,
                       btot, bbas, nBlocksScan);
    hipLaunchKernelGGL(scan3_kernel, dim3(nBlocksScan), dim3(1024), 0, stream,
                       ofs, cur, bbas, N_NODES);

    // range-split payload scatter (8 sequential passes, small live window each)
    const int nodesPerRange = (N_NODES + N_RANGES - 1) / N_RANGES;   // 12500
    for (int rg = 0; rg < N_RANGES; ++rg) {
        const int lo = rg * nodesPerRange;
        const int hi = min(lo + nodesPerRange, N_NODES);
        hipLaunchKernelGGL(fill_kernel, dim3((N_EDGES + 255) / 256), dim3(256), 0, stream,
                           src, dst, rel, norm, cur, pay, lo, hi);
    }

    // phase 3: aggregate + relu (each output written exactly once)
    hipLaunchKernelGGL(aggregate_kernel, dim3(N_NODES / 4), dim3(256), 0, stream,
                       T, pay, ofs, out);
}